// Round 1
// 412.077 us; speedup vs baseline: 1.0528x; 1.0528x over previous
//
#include <hip/hip_runtime.h>
#include <math.h>

// Problem constants
#define BB 128
#define SS 512
#define NN 32
#define DD 512
#define HH 2
#define MM (BB * NN)          // 4096 rows
#define DSQ (DD * DD)         // 262144

typedef short bf16x8 __attribute__((ext_vector_type(8)));
typedef float f32x4 __attribute__((ext_vector_type(4)));

__device__ __forceinline__ unsigned short f2bf(float f) {
    unsigned int u = __float_as_uint(f);
    u += 0x7fffu + ((u >> 16) & 1u);
    return (unsigned short)(u >> 16);
}
__device__ __forceinline__ float bf2f(unsigned short h) {
    return __uint_as_float(((unsigned int)h) << 16);
}
__device__ __forceinline__ void g2l16(const void* gp, void* lp) {
    __builtin_amdgcn_global_load_lds(
        (const __attribute__((address_space(1))) void*)gp,
        (__attribute__((address_space(3))) void*)lp, 16, 0, 0);
}

// ---------------------------------------------------------------------------
// adj + slot map fused: g_gt/g_lt [B,32,32] row-normalized; slot[b][s]
// ---------------------------------------------------------------------------
__global__ __launch_bounds__(256) void adj_k(const int* __restrict__ order,
                                             const int* __restrict__ pos,
                                             float* __restrict__ g_gt,
                                             float* __restrict__ g_lt,
                                             int* __restrict__ slot) {
    int b = blockIdx.x;
    __shared__ int ord[NN];
    __shared__ float sgt[NN][NN + 1];
    __shared__ float slt[NN][NN + 1];
    __shared__ float rs_gt[NN], rs_lt[NN];
    int tid = threadIdx.x;
    // slot init (barrier below orders these before the scatter at the end)
    slot[b * SS + tid] = -1;
    slot[b * SS + 256 + tid] = -1;
    if (tid < NN) ord[tid] = order[b * NN + tid];
    __syncthreads();
    for (int q = 0; q < 4; ++q) {
        int idx = tid + 256 * q;
        int n = idx >> 5, m = idx & 31;
        bool valid = (ord[n] > 0) && (ord[m] > 0) && (n != m);
        float eye = (n == m) ? 1.f : 0.f;
        bool gt = ord[n] > ord[m];
        sgt[n][m] = ((valid && gt) ? 1.f : 0.f) + eye;
        slt[n][m] = ((valid && !gt) ? 1.f : 0.f) + eye;
    }
    __syncthreads();
    if (tid < NN) {
        float s1 = 0.f, s2 = 0.f;
        for (int m = 0; m < NN; ++m) { s1 += sgt[tid][m]; s2 += slt[tid][m]; }
        rs_gt[tid] = s1; rs_lt[tid] = s2;
    }
    __syncthreads();
    for (int q = 0; q < 4; ++q) {
        int idx = tid + 256 * q;
        int n = idx >> 5, m = idx & 31;
        g_gt[b * 1024 + idx] = sgt[n][m] / rs_gt[n];
        g_lt[b * 1024 + idx] = slt[n][m] / rs_lt[n];
    }
    if (tid < NN) {
        int p = pos[b * NN + tid];
        if (p >= 0) slot[b * SS + p] = tid;
    }
}

// ---------------------------------------------------------------------------
// Weight prep (transpose + bf16) + gate-weight combine, one kernel.
// grid (14, 64): which<12 plain transpose; which 12,13 = combined gate W h=0,1
// ---------------------------------------------------------------------------
struct WSfull { const float* s[12]; int slot[12]; const float* w_g; };

__global__ __launch_bounds__(256) void wprep_k(WSfull w, unsigned short* __restrict__ Wt) {
    int which = blockIdx.x;
    int tile = blockIdx.y;
    int tr = (tile >> 3) * 64, tc = (tile & 7) * 64;
    __shared__ float c1[64][65];
    __shared__ float c2[64][65];
    int lc = threadIdx.x & 63, g4 = threadIdx.x >> 6;
    if (which < 12) {
        const float* src = w.s[which];
        unsigned short* dst = Wt + (size_t)w.slot[which] * DSQ;
        for (int i = 0; i < 16; ++i) {
            int lr = g4 * 16 + i;
            c1[lr][lc] = src[(size_t)(tr + lr) * DD + tc + lc];
        }
        __syncthreads();
        for (int i = 0; i < 16; ++i) {
            int lr = g4 * 16 + i;
            dst[(size_t)(tc + lr) * DD + tr + lc] = f2bf(c1[lc][lr]);
        }
    } else {
        int h = which - 12;
        const float* base = w.w_g + (size_t)h * 4 * DSQ;
        for (int i = 0; i < 16; ++i) {
            int lr = g4 * 16 + i;
            int k = tr + lr, n = tc + lc;
            float a  = base[(size_t)k * DD + n];
            float b2 = base[(size_t)(DD + k) * DD + n];
            float c  = base[(size_t)(2 * DD + k) * DD + n];
            float d4 = base[(size_t)(3 * DD + k) * DD + n];
            c1[lr][lc] = a + c + d4;
            c2[lr][lc] = b2 + c - d4;
        }
        __syncthreads();
        unsigned short* d1 = Wt + (size_t)(h * 8 + 4) * DSQ;
        unsigned short* d2 = Wt + (size_t)(h * 8 + 5) * DSQ;
        for (int i = 0; i < 16; ++i) {
            int lr = g4 * 16 + i;
            d1[(size_t)(tc + lr) * DD + tr + lc] = f2bf(c1[lc][lr]);
            d2[(size_t)(tc + lr) * DD + tr + lc] = f2bf(c2[lc][lr]);
        }
    }
}

// fp32 -> bf16 conversion (num_enc -> node0)
__global__ void conv_k(const float* __restrict__ x, unsigned short* __restrict__ o) {
    size_t i = ((size_t)blockIdx.x * 256 + threadIdx.x) * 4;
    float4 v = *(const float4*)(x + i);
    ushort4 r;
    r.x = f2bf(v.x); r.y = f2bf(v.y); r.z = f2bf(v.z); r.w = f2bf(v.w);
    *(ushort4*)(o + i) = r;
}

// ---------------------------------------------------------------------------
// MFMA GEMM, 64x64 tile, BK=64, 4 waves (each 32x32 via 2x2 MFMA 16x16x32).
//  MIX:  out = relu(g-mix(A@W^T) + bias)   (g applied post-GEMM, fp32)
//  GATE: gate = sigmoid(A1@W1+A2@W2+bias); out = gate*gin1+(1-gate)*gin2
//  else: out = relu(A@W^T (+A2@W2^T) + bias)
// LDS staging swizzle: row r (128 B), slot s at pos p = s ^ (r&7).
// ---------------------------------------------------------------------------
struct GA {
    const unsigned short* A1; const unsigned short* W1;
    const unsigned short* A2; const unsigned short* W2;
    const float* g; const float* bias;
    const unsigned short* gin1; const unsigned short* gin2;
    unsigned short* out;
};

template <bool MIX, bool DUAL, bool GATE>
__global__ __launch_bounds__(256) void mgemm_k(GA a0, GA a1) {
    GA g = (blockIdx.z == 0) ? a0 : a1;
    __shared__ __align__(16) unsigned short stag[8192];  // A [0,4096) B [4096,8192) shorts
    __shared__ float gsh[2048];                          // [2][32][32] fp32
    const int tid = threadIdx.x;
    const int lane = tid & 63;
    const int wave = tid >> 6;
    const int wr = wave & 1, wc = wave >> 1;
    const int bm = blockIdx.x * 64, bn = blockIdx.y * 64;

    if (MIX) {
        const float4* gsrc = (const float4*)(g.g + (size_t)(bm >> 5) * 1024);
        ((float4*)gsh)[tid] = gsrc[tid];
        ((float4*)gsh)[tid + 256] = gsrc[tid + 256];
    }

    f32x4 acc[2][2];
#pragma unroll
    for (int i = 0; i < 2; ++i)
#pragma unroll
        for (int j = 0; j < 2; ++j) {
            acc[i][j].x = 0.f; acc[i][j].y = 0.f; acc[i][j].z = 0.f; acc[i][j].w = 0.f;
        }

    // staging: entry e at LDS byte e*16; r=e>>3, pos=e&7 holds global slot s=pos^(r&7)
    const int r0 = tid >> 3,          s0 = (tid & 7) ^ (r0 & 7);
    const int r1 = (tid + 256) >> 3,  s1 = (tid & 7) ^ (r1 & 7);
    unsigned short* As = stag;
    unsigned short* Bs = stag + 4096;
    unsigned short* dA0 = As + wave * 512;
    unsigned short* dA1 = As + 2048 + wave * 512;
    unsigned short* dB0 = Bs + wave * 512;
    unsigned short* dB1 = Bs + 2048 + wave * 512;

    // fragment LDS offsets (shorts): [micro-k t][frag i]
    int aoff[2][2], boff[2][2];
#pragma unroll
    for (int t = 0; t < 2; ++t)
#pragma unroll
        for (int i = 0; i < 2; ++i) {
            int s = t * 4 + (lane >> 4);
            int p = s ^ (lane & 7);
            int m = wr * 32 + i * 16 + (lane & 15);
            aoff[t][i] = m * 64 + p * 8;
            int n = wc * 32 + i * 16 + (lane & 15);
            boff[t][i] = n * 64 + p * 8;
        }

    const int nsrc = DUAL ? 2 : 1;
    for (int src = 0; src < nsrc; ++src) {
        const unsigned short* A = src ? g.A2 : g.A1;
        const unsigned short* W = src ? g.W2 : g.W1;
        const unsigned short* Ab0 = A + (size_t)(bm + r0) * DD + s0 * 8;
        const unsigned short* Ab1 = A + (size_t)(bm + r1) * DD + s1 * 8;
        const unsigned short* Wb0 = W + (size_t)(bn + r0) * DD + s0 * 8;
        const unsigned short* Wb1 = W + (size_t)(bn + r1) * DD + s1 * 8;
        for (int k0 = 0; k0 < DD; k0 += 64) {
            g2l16(Ab0 + k0, dA0);
            g2l16(Ab1 + k0, dA1);
            g2l16(Wb0 + k0, dB0);
            g2l16(Wb1 + k0, dB1);
            __syncthreads();
            bf16x8 af[2][2], bf_[2][2];
#pragma unroll
            for (int t = 0; t < 2; ++t)
#pragma unroll
                for (int i = 0; i < 2; ++i) {
                    af[t][i]  = *(const bf16x8*)(As + aoff[t][i]);
                    bf_[t][i] = *(const bf16x8*)(Bs + boff[t][i]);
                }
#pragma unroll
            for (int t = 0; t < 2; ++t)
#pragma unroll
                for (int i = 0; i < 2; ++i)
#pragma unroll
                    for (int j = 0; j < 2; ++j)
                        acc[i][j] = __builtin_amdgcn_mfma_f32_16x16x32_bf16(
                            af[t][i], bf_[t][j], acc[i][j], 0, 0, 0);
            __syncthreads();
        }
    }

    if (!MIX) {
#pragma unroll
        for (int i = 0; i < 2; ++i) {
            int row = bm + wr * 32 + i * 16 + (lane >> 4) * 4;
#pragma unroll
            for (int j = 0; j < 2; ++j) {
                int col = bn + wc * 32 + j * 16 + (lane & 15);
                float bv = g.bias[col];
#pragma unroll
                for (int rg = 0; rg < 4; ++rg) {
                    float v = acc[i][j][rg] + bv;
                    size_t idx = (size_t)(row + rg) * DD + col;
                    if (GATE) {
                        float gg = 1.f / (1.f + __expf(-v));
                        float x1 = bf2f(g.gin1[idx]);
                        float x2 = bf2f(g.gin2[idx]);
                        g.out[idx] = f2bf(gg * x1 + (1.f - gg) * x2);
                    } else {
                        g.out[idx] = f2bf(fmaxf(v, 0.f));
                    }
                }
            }
        }
    } else {
        // stage raw C tile to LDS (fp32, 64x64 = 16 KB overlays staging)
        float* S = (float*)stag;
#pragma unroll
        for (int i = 0; i < 2; ++i) {
            int row = wr * 32 + i * 16 + (lane >> 4) * 4;
#pragma unroll
            for (int j = 0; j < 2; ++j) {
                int col = wc * 32 + j * 16 + (lane & 15);
#pragma unroll
                for (int rg = 0; rg < 4; ++rg) S[(row + rg) * 64 + col] = acc[i][j][rg];
            }
        }
        __syncthreads();
        // mix: out[n,d] = relu(sum_m g[bt][n][m] * S[bt*32+m][d] + bias[d])
#pragma unroll
        for (int t = 0; t < 4; ++t) {
            int task = t * 256 + tid;        // 1024 tasks: n(0..63) x dq(0..15)
            int n = task >> 4, dq = task & 15;
            int bt = n >> 5, nl = n & 31;
            float r0m = 0.f, r1m = 0.f, r2m = 0.f, r3m = 0.f;
            const float* gr = gsh + bt * 1024 + nl * 32;
            const float* Sb = S + bt * 32 * 64 + dq * 4;
#pragma unroll
            for (int m = 0; m < 32; ++m) {
                float gv = gr[m];
                f32x4 sv = *(const f32x4*)(Sb + m * 64);
                r0m += gv * sv.x; r1m += gv * sv.y; r2m += gv * sv.z; r3m += gv * sv.w;
            }
            float4 bv = *(const float4*)(g.bias + bn + dq * 4);
            ushort4 ov;
            ov.x = f2bf(fmaxf(r0m + bv.x, 0.f));
            ov.y = f2bf(fmaxf(r1m + bv.y, 0.f));
            ov.z = f2bf(fmaxf(r2m + bv.z, 0.f));
            ov.w = f2bf(fmaxf(r3m + bv.w, 0.f));
            *(ushort4*)(g.out + (size_t)(bm + n) * DD + bn + dq * 4) = ov;
        }
    }
}

// ---------------------------------------------------------------------------
// Outputs: gnn_info + partial max (y<16, vectorized float4) and
// num_embedding (y in [16,20), quarter per block)
// ---------------------------------------------------------------------------
__global__ __launch_bounds__(256) void gnn_k(const float* __restrict__ enc,
                                             const unsigned short* __restrict__ node,
                                             const int* __restrict__ slot,
                                             const float* __restrict__ num_enc,
                                             float* __restrict__ out_gnn,
                                             float* __restrict__ out_nemb,
                                             float* __restrict__ partial) {
    int b = blockIdx.x;
    int t = threadIdx.x;
    if (blockIdx.y >= 16) {
        // num_embedding: quarter of [N,D] per block
        int q = blockIdx.y - 16;
        size_t base = (size_t)b * NN * DD + (size_t)q * (NN * DD / 4);
        for (int it = 0; it < 4; ++it) {
            size_t i = base + (size_t)(it * 256 + t) * 4;
            float4 a = *(const float4*)(num_enc + i);
            ushort4 nb = *(const ushort4*)(node + i);
            float4 r;
            r.x = a.x + bf2f(nb.x);
            r.y = a.y + bf2f(nb.y);
            r.z = a.z + bf2f(nb.z);
            r.w = a.w + bf2f(nb.w);
            *(float4*)(out_nemb + i) = r;
        }
        return;
    }
    __shared__ int sl[32];
    __shared__ float4 red[128];
    int s0 = blockIdx.y * 32;
    if (t < 32) sl[t] = slot[b * SS + s0 + t];
    __syncthreads();
    const int dv = (t & 127) * 4;      // float offset within the 512-wide row
    const int sh = t >> 7;             // which 16-s half this thread handles
    float4 mx = {-INFINITY, -INFINITY, -INFINITY, -INFINITY};
#pragma unroll 4
    for (int i = 0; i < 16; ++i) {
        int sloc = sh * 16 + i;
        int s = s0 + sloc;
        int n = sl[sloc];              // wave-uniform
        size_t ebase = ((size_t)s * BB + b) * DD + dv;
        float4 v = *(const float4*)(enc + ebase);
        if (n >= 0) {
            ushort4 nb = *(const ushort4*)(node + ((size_t)b * NN + n) * DD + dv);
            v.x += bf2f(nb.x);
            v.y += bf2f(nb.y);
            v.z += bf2f(nb.z);
            v.w += bf2f(nb.w);
        }
        *(float4*)(out_gnn + ebase) = v;
        mx.x = fmaxf(mx.x, v.x);
        mx.y = fmaxf(mx.y, v.y);
        mx.z = fmaxf(mx.z, v.z);
        mx.w = fmaxf(mx.w, v.w);
    }
    if (sh == 1) red[t & 127] = mx;
    __syncthreads();
    if (sh == 0) {
        float4 o = red[t];
        mx.x = fmaxf(mx.x, o.x);
        mx.y = fmaxf(mx.y, o.y);
        mx.z = fmaxf(mx.z, o.z);
        mx.w = fmaxf(mx.w, o.w);
        *(float4*)(partial + ((size_t)b * 16 + blockIdx.y) * DD + dv) = mx;
    }
}

__global__ void pmax_k(const float* __restrict__ partial, float* __restrict__ out_prob) {
    int i = blockIdx.x * 256 + threadIdx.x;
    if (i >= BB * DD) return;
    int b = i >> 9, d = i & 511;
    float m = -INFINITY;
    for (int c = 0; c < 16; ++c) m = fmaxf(m, partial[((size_t)b * 16 + c) * DD + d]);
    out_prob[i] = m;
}

// ---------------------------------------------------------------------------
// Host launch
// ---------------------------------------------------------------------------
extern "C" void kernel_launch(void* const* d_in, const int* in_sizes, int n_in,
                              void* d_out, int out_size, void* d_ws, size_t ws_size,
                              hipStream_t stream) {
    const float* enc     = (const float*)d_in[0];
    const float* num_enc = (const float*)d_in[1];
    const int*   pos     = (const int*)d_in[2];
    const int*   order   = (const int*)d_in[3];
    const float* w_n1a = (const float*)d_in[4];  const float* b_n1a = (const float*)d_in[5];
    const float* w_n1b = (const float*)d_in[6];  const float* b_n1b = (const float*)d_in[7];
    const float* w_n2a = (const float*)d_in[8];  const float* b_n2a = (const float*)d_in[9];
    const float* w_n2b = (const float*)d_in[10]; const float* b_n2b = (const float*)d_in[11];
    const float* w_g   = (const float*)d_in[12]; const float* b_g   = (const float*)d_in[13];
    const float* w_o   = (const float*)d_in[14]; const float* b_o   = (const float*)d_in[15];

    char* wp = (char*)d_ws;
    float* g_gt = (float*)wp;        wp += (size_t)BB * NN * NN * 4;
    float* g_lt = (float*)wp;        wp += (size_t)BB * NN * NN * 4;
    float* partial = (float*)wp;     wp += (size_t)BB * 16 * DD * 4;
    int* slot = (int*)wp;            wp += (size_t)BB * SS * 4;
    unsigned short* Wt = (unsigned short*)wp;    wp += (size_t)16 * DSQ * 2;
    unsigned short* node0 = (unsigned short*)wp; wp += (size_t)MM * DD * 2;
    unsigned short* nodeA = (unsigned short*)wp; wp += (size_t)MM * DD * 2;
    unsigned short* nodeB = (unsigned short*)wp; wp += (size_t)MM * DD * 2;
    unsigned short* ni1 = (unsigned short*)wp;   wp += (size_t)MM * DD * 2;
    unsigned short* ni2 = (unsigned short*)wp;   wp += (size_t)MM * DD * 2;
    unsigned short* t1 = (unsigned short*)wp;    wp += (size_t)MM * DD * 2;
    unsigned short* t2 = (unsigned short*)wp;    wp += (size_t)MM * DD * 2;

    float* out_gnn  = (float*)d_out;
    float* out_nemb = out_gnn + (size_t)SS * BB * DD;
    float* out_prob = out_nemb + (size_t)BB * NN * DD;

    // Setup (3 dispatches)
    adj_k<<<BB, 256, 0, stream>>>(order, pos, g_gt, g_lt, slot);

    WSfull wsrc;
    const float* srcs[12] = {w_n1a, w_n1b, w_n2a, w_n2b, w_o, w_o + DSQ,
                             w_n1a + DSQ, w_n1b + DSQ, w_n2a + DSQ, w_n2b + DSQ,
                             w_o + 2 * DSQ, w_o + 3 * DSQ};
    int slots[12] = {0, 1, 2, 3, 6, 7, 8, 9, 10, 11, 14, 15};
    for (int i = 0; i < 12; ++i) { wsrc.s[i] = srcs[i]; wsrc.slot[i] = slots[i]; }
    wsrc.w_g = w_g;
    wprep_k<<<dim3(14, 64), 256, 0, stream>>>(wsrc, Wt);
    conv_k<<<(MM * DD) / 1024, 256, 0, stream>>>(num_enc, node0);

    dim3 dgrid(MM / 64, DD / 64, 2);   // 64x8x2 = 1024 blocks
    dim3 sgrid(MM / 64, DD / 64, 1);   // 512 blocks

    const unsigned short* nodeIn = node0;
    for (int h = 0; h < HH; ++h) {
        unsigned short* nodeOut = (h == 0) ? nodeA : nodeB;
        const unsigned short* Wh = Wt + (size_t)h * 8 * DSQ;

        // stage A: ni1 = relu(g_gt-mix(x@W1a)+b); ni2 = relu(g_lt-mix(x@W2a)+b)
        GA sa0 = {nodeIn, Wh + 0 * DSQ, nullptr, nullptr, g_gt, b_n1a + h * DD,
                  nullptr, nullptr, ni1};
        GA sa1 = {nodeIn, Wh + 2 * DSQ, nullptr, nullptr, g_lt, b_n2a + h * DD,
                  nullptr, nullptr, ni2};
        mgemm_k<true, false, false><<<dgrid, 256, 0, stream>>>(sa0, sa1);

        // stage B: t1 = relu(g_gt-mix(ni1@W1b)+b); t2 = relu(g_lt-mix(ni2@W2b)+b)
        GA sb0 = {ni1, Wh + 1 * DSQ, nullptr, nullptr, g_gt, b_n1b + h * DD,
                  nullptr, nullptr, t1};
        GA sb1 = {ni2, Wh + 3 * DSQ, nullptr, nullptr, g_lt, b_n2b + h * DD,
                  nullptr, nullptr, t2};
        mgemm_k<true, false, false><<<dgrid, 256, 0, stream>>>(sb0, sb1);

        // gate: info = gate*t1 + (1-gate)*t2  -> ni1 (reused as info buffer)
        GA gg = {t1, Wh + 4 * DSQ, t2, Wh + 5 * DSQ, nullptr, b_g + h * DD, t1, t2, ni1};
        mgemm_k<false, true, true><<<sgrid, 256, 0, stream>>>(gg, gg);

        // out: node = relu(x@Wo_a + info@Wo_b + b)
        GA go = {nodeIn, Wh + 6 * DSQ, ni1, Wh + 7 * DSQ, nullptr, b_o + h * DD,
                 nullptr, nullptr, nodeOut};
        mgemm_k<false, true, false><<<sgrid, 256, 0, stream>>>(go, go);

        nodeIn = nodeOut;
    }
    const unsigned short* nodeF = nodeIn;

    // Outputs (2 dispatches)
    gnn_k<<<dim3(BB, 20), 256, 0, stream>>>(enc, nodeF, slot, num_enc,
                                            out_gnn, out_nemb, partial);
    pmax_k<<<(BB * DD) / 256, 256, 0, stream>>>(partial, out_prob);
}